// Round 8
// baseline (739.235 us; speedup 1.0000x reference)
//
#include <hip/hip_runtime.h>

// ThreeStateExplorer: B=256 particles, T=100k steps.
//   k[t]   = inclusive cumsum(states==2)
//   vel[t] = (states[t]==2 ? 0 : e0s[b,k[t]] * (states[t]==0 ? sp0 : sp1))
//   X[t]   = x0 + DT * cumsum(vel)
//
// R10: IPT=16 retry (7 chunks instead of 13), now safe because stores go
// through the R9 wave-local LDS transpose (full-line 1KB-contiguous wave
// stores; R7's 3x write amplification came from partial-line 96B-stride
// stores, mechanism now absent). Two-pass transpose: pass p covers the
// contiguous output f4 range [384p,384p+384) of the wave's 12KB region,
// produced exactly by lanes [32p,32p+32) (f = lane*12+m) — a correct
// contiguous split (R8's interleaved split was not). Producer pad 13 f4/lane
// (4-way banks ~1.58x, ~2us); consumer reads phys = f + f/12, ~stride-1.
// Same-wave DS ordering => no new barriers (validated by R9).
// Ledger: barriers x(R3), occupancy x(R4), gather-staging x(R5),
// chunk-count-at-strided-stores x(R7), store-coalescing WIN(R9, -40us).

#define NT    1024          // threads per block (16 waves)
#define IPT   16            // elements per thread per chunk
#define CHUNK (NT * IPT)    // 16384
#define NW    (NT / 64)     // 16 waves
#define SLICE 416           // padded f4 slots per wave slice (32 lanes * 13)

__device__ __forceinline__ void load_states(const int* __restrict__ st, int lim,
                                            int e0i, int out[IPT]) {
    if (e0i + IPT <= lim) {
        int4 a = *(const int4*)(st + e0i);
        int4 b = *(const int4*)(st + e0i + 4);
        int4 c = *(const int4*)(st + e0i + 8);
        int4 d = *(const int4*)(st + e0i + 12);
        out[0]  = a.x; out[1]  = a.y; out[2]  = a.z; out[3]  = a.w;
        out[4]  = b.x; out[5]  = b.y; out[6]  = b.z; out[7]  = b.w;
        out[8]  = c.x; out[9]  = c.y; out[10] = c.z; out[11] = c.w;
        out[12] = d.x; out[13] = d.y; out[14] = d.z; out[15] = d.w;
    } else {
        #pragma unroll
        for (int j = 0; j < IPT; ++j)
            out[j] = (e0i + j < lim) ? st[e0i + j] : 3;  // sentinel: vel=0, no tumble
    }
}

__global__ __launch_bounds__(NT)
void traj_kernel(const int*   __restrict__ states,   // (B,T)
                 const float* __restrict__ e0s,      // (B,T+1,3)
                 const float* __restrict__ sp0v,     // (B,)
                 const float* __restrict__ sp1v,     // (B,)
                 const float* __restrict__ x0,       // (B,3)
                 float*       __restrict__ X,        // (B,T,3)
                 int T)
{
    const int b    = blockIdx.x;
    const int tid  = threadIdx.x;
    const int lane = tid & 63;
    const int wid  = tid >> 6;

    __shared__ float4 s_t[NW * SLICE];  // 104 KB: padded 6.5KB transpose slice/wave
    __shared__ int    s_wi[NW];
    __shared__ float  s_wf[NW][3];

    const int*   st = states + (size_t)b * T;
    const float* er = e0s    + (size_t)b * (T + 1) * 3;
    float*       xr = X      + (size_t)b * T * 3;
    const float sp0 = sp0v[b], sp1 = sp1v[b];
    const float x00 = x0[3 * b + 0], x01 = x0[3 * b + 1], x02 = x0[3 * b + 2];

    int   kc  = 0;                          // tumble-count carry
    float pcx = 0.f, pcy = 0.f, pcz = 0.f;  // position carry (un-scaled vel sum)

    int cur[IPT];
    load_states(st, T, tid * IPT, cur);

    for (int base = 0; base < T; base += CHUNK) {
        // ---- prefetch next chunk's states (in flight under this chunk's work)
        int nxt[IPT];
        const bool has_next = (base + CHUNK) < T;   // wave-uniform
        if (has_next) load_states(st, T, base + CHUNK + tid * IPT, nxt);

        // ---- tumble-count block scan
        int c = 0;
        #pragma unroll
        for (int j = 0; j < IPT; ++j) c += (cur[j] == 2);
        int incl = c;
        #pragma unroll
        for (int d = 1; d < 64; d <<= 1) {
            int n = __shfl_up(incl, d, 64);
            if (lane >= d) incl += n;
        }
        if (lane == 63) s_wi[wid] = incl;
        __syncthreads();                                   // barrier 1
        int wex = 0, btot = 0;
        #pragma unroll
        for (int w = 0; w < NW; ++w) {
            int t = s_wi[w];
            wex  += (w < wid) ? t : 0;
            btot += t;
        }
        int k = kc + wex + (incl - c);    // tumbles strictly before my 1st elem

        // ---- batched direct gathers (L2/L3 absorbs window reuse — R5 measured)
        float ex[IPT], ey[IPT], ez[IPT];
        #pragma unroll
        for (int j = 0; j < IPT; ++j) {
            const int s = cur[j];
            k += (s == 2);                // inclusive count; sp=0 at tumble
            const float sp = (s == 0) ? sp0 : ((s == 1) ? sp1 : 0.f);
            const float* e = er + (size_t)k * 3;   // k <= T: always in bounds
            ex[j] = e[0] * sp;
            ey[j] = e[1] * sp;
            ez[j] = e[2] * sp;
        }

        // ---- thread-local inclusive prefix, in place
        float px = 0.f, py = 0.f, pz = 0.f;
        #pragma unroll
        for (int j = 0; j < IPT; ++j) {
            px += ex[j]; ex[j] = px;
            py += ey[j]; ey[j] = py;
            pz += ez[j]; ez[j] = pz;
        }

        // ---- block scan (float3) of thread totals
        float ix = px, iy = py, iz = pz;
        #pragma unroll
        for (int d = 1; d < 64; d <<= 1) {
            float nx = __shfl_up(ix, d, 64);
            float ny = __shfl_up(iy, d, 64);
            float nz = __shfl_up(iz, d, 64);
            if (lane >= d) { ix += nx; iy += ny; iz += nz; }
        }
        if (lane == 63) { s_wf[wid][0] = ix; s_wf[wid][1] = iy; s_wf[wid][2] = iz; }
        __syncthreads();                                   // barrier 2
        float wfx = 0.f, wfy = 0.f, wfz = 0.f, btx = 0.f, bty = 0.f, btz = 0.f;
        #pragma unroll
        for (int w = 0; w < NW; ++w) {
            float tx = s_wf[w][0], ty = s_wf[w][1], tz = s_wf[w][2];
            if (w < wid) { wfx += tx; wfy += ty; wfz += tz; }
            btx += tx; bty += ty; btz += tz;
        }
        const float bx = pcx + wfx + (ix - px);
        const float by = pcy + wfy + (iy - py);
        const float bz = pcz + wfz + (iz - pz);

        // ---- finalize + store
        #define FX(j) (x00 + (bx + ex[j]) * 0.1f)
        #define FY(j) (x01 + (by + ey[j]) * 0.1f)
        #define FZ(j) (x02 + (bz + ez[j]) * 0.1f)
        if (base + CHUNK <= T) {
            // Two-pass wave-local transpose. Wave region = 768 f4 (12KB).
            // Pass p: output f4 range [384p, 384p+384), produced by lanes
            // [32p,32p+32) (f = lane*12+m). Producer at padded (lane&31)*13+m;
            // consumer reads logical f at phys f + f/12 (~stride-1), stores
            // 6 x 1KB fully contiguous. Same-wave DS ordering covers the
            // producer->consumer and pass0-read->pass1-write hazards (R9).
            float4* wslice = s_t + wid * SLICE;
            float4* gbase  = (float4*)(xr + (size_t)base * 3) + (size_t)wid * 768;
            #pragma unroll
            for (int p = 0; p < 2; ++p) {
                if ((lane >> 5) == p) {
                    const int l  = lane & 31;
                    const int j0 = 0;            // elements 8p+0 .. 8p+7? no:
                    // pass p stages this lane's FULL 16 elements (lanes 32p..)
                    float4* wp = wslice + l * 13;
                    #define PACK3(m, a0, a1, a2, a3)                               \
                        wp[m]     = make_float4(FX(a0), FY(a0), FZ(a0), FX(a1));   \
                        wp[m + 1] = make_float4(FY(a1), FZ(a1), FX(a2), FY(a2));   \
                        wp[m + 2] = make_float4(FZ(a2), FX(a3), FY(a3), FZ(a3));
                    PACK3(0,  0,  1,  2,  3)
                    PACK3(3,  4,  5,  6,  7)
                    PACK3(6,  8,  9, 10, 11)
                    PACK3(9, 12, 13, 14, 15)
                    #undef PACK3
                    (void)j0;
                }
                #pragma unroll
                for (int m = 0; m < 6; ++m) {
                    const int f = m * 64 + lane;            // logical f4 in pass
                    gbase[p * 384 + f] = wslice[f + f / 12]; // phys = pad-adjusted
                }
            }
        } else {
            const int e0i = base + tid * IPT;
            #pragma unroll
            for (int j = 0; j < IPT; ++j)
                if (e0i + j < T) {
                    float* d = xr + (size_t)(e0i + j) * 3;
                    d[0] = FX(j); d[1] = FY(j); d[2] = FZ(j);
                }
        }
        #undef FX
        #undef FY
        #undef FZ

        // ---- carries (uniform; s_wi next write after this B2, s_wf next write
        //      after next B1; s_t is wave-private — no cross-wave hazard)
        kc  += btot;
        pcx += btx; pcy += bty; pcz += btz;

        #pragma unroll
        for (int j = 0; j < IPT; ++j) cur[j] = nxt[j];
    }
}

extern "C" void kernel_launch(void* const* d_in, const int* in_sizes, int n_in,
                              void* d_out, int out_size, void* d_ws, size_t ws_size,
                              hipStream_t stream) {
    const int*   states = (const int*)  d_in[0];
    const float* e0s    = (const float*)d_in[1];
    const float* sp0    = (const float*)d_in[2];
    const float* sp1    = (const float*)d_in[3];
    const float* x0     = (const float*)d_in[4];
    float*       X      = (float*)d_out;

    const int B = in_sizes[2];            // speed_0 has one entry per particle
    const int T = in_sizes[0] / B;        // states is (B,T)

    traj_kernel<<<dim3(B), dim3(NT), 0, stream>>>(states, e0s, sp0, sp1, x0, X, T);
}